// Round 1
// baseline (359.331 us; speedup 1.0000x reference)
//
#include <hip/hip_runtime.h>

#define NROWS 8192
#define NCOLSX 1024

typedef __attribute__((ext_vector_type(8))) short bf16x8;
typedef __attribute__((ext_vector_type(4))) float f32x4;
typedef __attribute__((ext_vector_type(4))) int i32x4;
typedef __attribute__((ext_vector_type(4))) unsigned short u16x4;

union FragU { i32x4 q; bf16x8 v; };

__device__ __forceinline__ unsigned short bf16h(float f) {
  unsigned int u = __float_as_uint(f);
  unsigned int r = (u + 0x7FFFu + ((u >> 16) & 1u)) >> 16;
  return (unsigned short)r;
}
__device__ __forceinline__ unsigned short bf16l(float f, unsigned short h) {
  float fh = __uint_as_float(((unsigned int)h) << 16);
  return bf16h(f - fh);
}

#define GLOAD16(gp, lp) __builtin_amdgcn_global_load_lds( \
    (const __attribute__((address_space(1))) void*)(gp),  \
    (__attribute__((address_space(3))) void*)(lp), 16, 0, 0)

// ---------------- P1: split x into bf16 hi/lo, transposed to [d][n] ----------
__global__ __launch_bounds__(256) void split_transpose_x(
    const float* __restrict__ x,
    unsigned short* __restrict__ xhT, unsigned short* __restrict__ xlT) {
  __shared__ float tile[64][65];
  const int r0 = blockIdx.x * 64;   // n-dim
  const int c0 = blockIdx.y * 64;   // d-dim
  const int t = threadIdx.x;
  const int tr = t >> 4, tc = t & 15;
#pragma unroll
  for (int rr = 0; rr < 4; ++rr) {
    int row = tr * 4 + rr;
    f32x4 v = *(const f32x4*)(x + (size_t)(r0 + row) * NCOLSX + c0 + tc * 4);
    tile[row][tc * 4 + 0] = v.x;
    tile[row][tc * 4 + 1] = v.y;
    tile[row][tc * 4 + 2] = v.z;
    tile[row][tc * 4 + 3] = v.w;
  }
  __syncthreads();
#pragma unroll
  for (int rr = 0; rr < 4; ++rr) {
    int j = tr * 4 + rr;  // local d index
    u16x4 h, lo;
#pragma unroll
    for (int c = 0; c < 4; ++c) {
      float v = tile[tc * 4 + c][j];
      unsigned short hv = bf16h(v);
      h[c] = hv;
      lo[c] = bf16l(v, hv);
    }
    size_t o = (size_t)(c0 + j) * NROWS + r0 + tc * 4;
    *(u16x4*)(xhT + o) = h;
    *(u16x4*)(xlT + o) = lo;
  }
}

// ---------------- P2: build packed Toeplitz A-tiles (hi/lo) -----------------
// Tile tau (Delta = tau*32 - 96): 128x32 values ext[Delta + row - kk],
// packed in MFMA fragment order: byte = f*1024 + lane*16 + e*2,
// value(f,lane,e) = ext[Delta + 16f + (lane&15) - 8*(lane>>4) - e].
__global__ __launch_bounds__(256) void build_atiles(
    const float* __restrict__ a,
    unsigned short* __restrict__ Ah, unsigned short* __restrict__ Al) {
  const int tau = blockIdx.x;        // 0..255
  const int delta = tau * 32 - 96;
  for (int p = threadIdx.x; p < 512; p += 256) {
    int f = p >> 6, l = p & 63;
    int baseT = delta + 16 * f + (l & 15) - 8 * (l >> 4);
    size_t o = (size_t)tau * 4096 + f * 512 + l * 8;
#pragma unroll
    for (int e = 0; e < 8; ++e) {
      int tt = baseT - e;
      float v = (tt >= 0 && tt < NROWS) ? a[tt] : 0.f;
      unsigned short hv = bf16h(v);
      Ah[o + e] = hv;
      Al[o + e] = bf16l(v, hv);
    }
  }
}

// ---------------- main MFMA kernel ------------------------------------------
// Grid: 4352 = 544 chunks * 8 col-blocks. Chunk = up to 16 K-steps of 32.
__global__ __launch_bounds__(256, 2) void conv_mfma(
    const unsigned short* __restrict__ xhT, const unsigned short* __restrict__ xlT,
    const unsigned short* __restrict__ Ah, const unsigned short* __restrict__ Al,
    float* __restrict__ out) {
  __shared__ char lds[32768];
  char* ldsAh = lds;
  char* ldsAl = lds + 8192;
  char* ldsXh = lds + 16384;
  char* ldsXl = lds + 24576;

  const int t = threadIdx.x;
  const int lane = t & 63;
  const int wid = t >> 6;
  const int wm = wid >> 1, wn = wid & 1;

  // decode block -> (I, J, chunk s0)
  const int J = blockIdx.x & 7;
  const int q = blockIdx.x >> 3;
  int I = 0, accq = 0;
  while (accq + ((I + 4) >> 2) <= q) { accq += (I + 4) >> 2; ++I; }
  const int s0 = q - accq;
  const int kstart = s0 * 512;
  const int kmaxI = (I + 1) * 128;
  const int kend = (kstart + 512 < kmaxI) ? (kstart + 512) : kmaxI;

  f32x4 acc[4][4] = {};

  const char* Ah_b = (const char*)Ah;
  const char* Al_b = (const char*)Al;
  const char* xh_b = (const char*)xhT;
  const char* xl_b = (const char*)xlT;

  const int j0 = t >> 2, kc = t & 3;
  const size_t xrow0 = (size_t)(J * 128 + j0) * (NROWS * 2);
  const size_t xrow1 = (size_t)(J * 128 + j0 + 64) * (NROWS * 2);

  for (int k0 = kstart; k0 < kend; k0 += 32) {
    __syncthreads();
    const int tau = ((I * 128 - k0) + 96) >> 5;
    const char* sAh = Ah_b + (size_t)tau * 8192;
    const char* sAl = Al_b + (size_t)tau * 8192;
    const size_t xoff = (size_t)k0 * 2 + kc * 16;
    GLOAD16(sAh + t * 16,        ldsAh + wid * 1024);
    GLOAD16(sAh + 4096 + t * 16, ldsAh + 4096 + wid * 1024);
    GLOAD16(sAl + t * 16,        ldsAl + wid * 1024);
    GLOAD16(sAl + 4096 + t * 16, ldsAl + 4096 + wid * 1024);
    GLOAD16(xh_b + xrow0 + xoff, ldsXh + wid * 1024);
    GLOAD16(xh_b + xrow1 + xoff, ldsXh + 4096 + wid * 1024);
    GLOAD16(xl_b + xrow0 + xoff, ldsXl + wid * 1024);
    GLOAD16(xl_b + xrow1 + xoff, ldsXl + 4096 + wid * 1024);
    asm volatile("s_waitcnt vmcnt(0)" ::: "memory");
    __syncthreads();

    FragU xh[4], xl[4];
#pragma unroll
    for (int ni = 0; ni < 4; ++ni) {
      int jl = (wn * 4 + ni) * 16 + (lane & 15);
      int off = jl * 64 + (lane >> 4) * 16;
      xh[ni].q = *(const i32x4*)(ldsXh + off);
      xl[ni].q = *(const i32x4*)(ldsXl + off);
    }
#pragma unroll
    for (int mi = 0; mi < 4; ++mi) {
      int f = wm * 4 + mi;
      FragU ah, al;
      ah.q = *(const i32x4*)(ldsAh + f * 1024 + lane * 16);
      al.q = *(const i32x4*)(ldsAl + f * 1024 + lane * 16);
#pragma unroll
      for (int ni = 0; ni < 4; ++ni) {
        acc[mi][ni] = __builtin_amdgcn_mfma_f32_16x16x32_bf16(ah.v, xh[ni].v, acc[mi][ni], 0, 0, 0);
        acc[mi][ni] = __builtin_amdgcn_mfma_f32_16x16x32_bf16(ah.v, xl[ni].v, acc[mi][ni], 0, 0, 0);
        acc[mi][ni] = __builtin_amdgcn_mfma_f32_16x16x32_bf16(al.v, xh[ni].v, acc[mi][ni], 0, 0, 0);
      }
    }
  }

  // accumulate into out (C/D layout: col=lane&15, row=(lane>>4)*4+r)
#pragma unroll
  for (int mi = 0; mi < 4; ++mi) {
    int grow = I * 128 + wm * 64 + mi * 16 + (lane >> 4) * 4;
#pragma unroll
    for (int ni = 0; ni < 4; ++ni) {
      int gcol = J * 128 + wn * 64 + ni * 16 + (lane & 15);
#pragma unroll
      for (int r = 0; r < 4; ++r) {
        unsafeAtomicAdd(out + (size_t)(grow + r) * NCOLSX + gcol, acc[mi][ni][r]);
      }
    }
  }
}

// ---------------- fallback (ws too small): plain fp32 -----------------------
__global__ __launch_bounds__(256) void naive_conv(
    const float* __restrict__ a, const float* __restrict__ x, float* __restrict__ out) {
  const int j = blockIdx.x * 256 + threadIdx.x;
  const int i0 = blockIdx.y * 32;
  float accv[32];
#pragma unroll
  for (int r = 0; r < 32; ++r) accv[r] = 0.f;
  for (int k = 0; k < i0; ++k) {
    float xv = x[(size_t)k * NCOLSX + j];
#pragma unroll
    for (int r = 0; r < 32; ++r) accv[r] += a[i0 + r - k] * xv;
  }
  for (int k = i0; k < i0 + 32; ++k) {
    float xv = x[(size_t)k * NCOLSX + j];
    for (int r = k - i0; r < 32; ++r) accv[r] += a[i0 + r - k] * xv;
  }
#pragma unroll
  for (int r = 0; r < 32; ++r) out[(size_t)(i0 + r) * NCOLSX + j] = accv[r];
}

extern "C" void kernel_launch(void* const* d_in, const int* in_sizes, int n_in,
                              void* d_out, int out_size, void* d_ws, size_t ws_size,
                              hipStream_t stream) {
  const float* a = (const float*)d_in[0];
  const float* x = (const float*)d_in[1];
  float* out = (float*)d_out;

  const size_t OFF_XH = 0;
  const size_t OFF_XL = (size_t)NROWS * NCOLSX * 2;           // 16 MiB
  const size_t OFF_AH = OFF_XL + (size_t)NROWS * NCOLSX * 2;  // 32 MiB
  const size_t OFF_AL = OFF_AH + (size_t)256 * 8192;
  const size_t NEEDED = OFF_AL + (size_t)256 * 8192;          // ~36 MiB

  if (ws_size < NEEDED) {
    naive_conv<<<dim3(NCOLSX / 256, NROWS / 32), 256, 0, stream>>>(a, x, out);
    return;
  }

  char* ws = (char*)d_ws;
  unsigned short* xhT = (unsigned short*)(ws + OFF_XH);
  unsigned short* xlT = (unsigned short*)(ws + OFF_XL);
  unsigned short* AhT = (unsigned short*)(ws + OFF_AH);
  unsigned short* AlT = (unsigned short*)(ws + OFF_AL);

  hipMemsetAsync(d_out, 0, (size_t)NROWS * NCOLSX * sizeof(float), stream);
  split_transpose_x<<<dim3(NROWS / 64, NCOLSX / 64), 256, 0, stream>>>(x, xhT, xlT);
  build_atiles<<<256, 256, 0, stream>>>(a, AhT, AlT);
  conv_mfma<<<4352, 256, 0, stream>>>(xhT, xlT, AhT, AlT, out);
}

// Round 2
// 315.895 us; speedup vs baseline: 1.1375x; 1.1375x over previous
//
#include <hip/hip_runtime.h>

#define NROWS 8192
#define NCOLSX 1024

typedef __attribute__((ext_vector_type(8))) short bf16x8;
typedef __attribute__((ext_vector_type(4))) float f32x4;
typedef __attribute__((ext_vector_type(4))) int i32x4;
typedef __attribute__((ext_vector_type(4))) unsigned short u16x4;

union FragU { i32x4 q; bf16x8 v; };

__device__ __forceinline__ unsigned short bf16h(float f) {
  unsigned int u = __float_as_uint(f);
  unsigned int r = (u + 0x7FFFu + ((u >> 16) & 1u)) >> 16;
  return (unsigned short)r;
}

#define GLOAD16(gp, lp) __builtin_amdgcn_global_load_lds( \
    (const __attribute__((address_space(1))) void*)(gp),  \
    (__attribute__((address_space(3))) void*)(lp), 16, 0, 0)

// ---------------- P1: x -> bf16, transposed to [d][n] -----------------------
__global__ __launch_bounds__(256) void bf16_transpose_x(
    const float* __restrict__ x, unsigned short* __restrict__ xhT) {
  __shared__ float tile[64][65];
  const int r0 = blockIdx.x * 64;   // n-dim
  const int c0 = blockIdx.y * 64;   // d-dim
  const int t = threadIdx.x;
  const int tr = t >> 4, tc = t & 15;
#pragma unroll
  for (int rr = 0; rr < 4; ++rr) {
    int row = tr * 4 + rr;
    f32x4 v = *(const f32x4*)(x + (size_t)(r0 + row) * NCOLSX + c0 + tc * 4);
    tile[row][tc * 4 + 0] = v.x;
    tile[row][tc * 4 + 1] = v.y;
    tile[row][tc * 4 + 2] = v.z;
    tile[row][tc * 4 + 3] = v.w;
  }
  __syncthreads();
#pragma unroll
  for (int rr = 0; rr < 4; ++rr) {
    int j = tr * 4 + rr;  // local d index
    u16x4 h;
#pragma unroll
    for (int c = 0; c < 4; ++c) h[c] = bf16h(tile[tc * 4 + c][j]);
    *(u16x4*)(xhT + (size_t)(c0 + j) * NROWS + r0 + tc * 4) = h;
  }
}

// ---------------- P2: packed Toeplitz A-tiles (bf16, BK=64) -----------------
// Tile tau (Delta = tau*64 - 64): 128x64 values ext[Delta + row - k],
// frag-packed for 16x16x32: elem idx = (s*8+f)*512 + l*8 + e,
// value = ext[Delta + 16f + (l&15) - s*32 - (l>>4)*8 - e].
__global__ __launch_bounds__(256) void build_atiles(
    const float* __restrict__ a, unsigned short* __restrict__ Ah) {
  const int tau = blockIdx.x;        // 0..127
  const int delta = tau * 64 - 64;
  const int t = threadIdx.x;
#pragma unroll
  for (int n = 0; n < 32; ++n) {
    int idx = n * 256 + t;
    int e = idx & 7, l = (idx >> 3) & 63, sf = idx >> 9;
    int f = sf & 7, s = sf >> 3;
    int tt = delta + 16 * f + (l & 15) - s * 32 - (l >> 4) * 8 - e;
    float v = (tt >= 0 && tt < NROWS) ? a[tt] : 0.f;
    Ah[(size_t)tau * 8192 + idx] = bf16h(v);
  }
}

// ---------------- main MFMA kernel (pure bf16, BK=64) -----------------------
// Grid: 4352 = 544 chunks * 8 col-blocks. Chunk = up to 8 K-steps of 64.
__global__ __launch_bounds__(256, 2) void conv_mfma(
    const unsigned short* __restrict__ xhT, const unsigned short* __restrict__ Ah,
    float* __restrict__ out) {
  __shared__ char lds[32768];
  char* ldsA = lds;          // 16KB frag-packed A tile
  char* ldsX = lds + 16384;  // 16KB: two s-blocks, each [128 j][64B of k]

  const int t = threadIdx.x;
  const int lane = t & 63;
  const int wid = t >> 6;
  const int wm = wid >> 1, wn = wid & 1;

  // decode block -> (I, J, chunk s0)
  const int J = blockIdx.x & 7;
  const int q = blockIdx.x >> 3;
  int I = 0, accq = 0;
  while (accq + ((I + 4) >> 2) <= q) { accq += (I + 4) >> 2; ++I; }
  const int s0 = q - accq;
  const int kstart = s0 * 512;
  const int kmaxI = (I + 1) * 128;
  const int kend = (kstart + 512 < kmaxI) ? (kstart + 512) : kmaxI;

  f32x4 acc[4][4] = {};

  const char* Ah_b = (const char*)Ah;
  const char* xh_b = (const char*)xhT;

  // X staging: sweep w -> s = w>>1, local row r = (w&1)*64 + (t>>2), col byte (t&3)*16
  size_t xsrc[4];
#pragma unroll
  for (int w = 0; w < 4; ++w)
    xsrc[w] = (size_t)(J * 128 + (w & 1) * 64 + (t >> 2)) * (NROWS * 2)
              + (w >> 1) * 64 + (t & 3) * 16;

  for (int k0 = kstart; k0 < kend; k0 += 64) {
    __syncthreads();
    const int tau = ((I * 128 - k0) >> 6) + 1;
    const char* sA = Ah_b + (size_t)tau * 16384;
    const size_t koff = (size_t)k0 * 2;
#pragma unroll
    for (int w = 0; w < 4; ++w) {
      GLOAD16(sA + w * 4096 + t * 16, ldsA + w * 4096 + t * 16);
      GLOAD16(xh_b + xsrc[w] + koff, ldsX + w * 4096 + t * 16);
    }
    asm volatile("s_waitcnt vmcnt(0)" ::: "memory");
    __syncthreads();

    FragU xf[2][4];
#pragma unroll
    for (int s = 0; s < 2; ++s)
#pragma unroll
      for (int ni = 0; ni < 4; ++ni) {
        int off = s * 8192 + (wn * 64 + ni * 16 + (lane & 15)) * 64 + (lane >> 4) * 16;
        xf[s][ni].q = *(const i32x4*)(ldsX + off);
      }
#pragma unroll
    for (int mi = 0; mi < 4; ++mi)
#pragma unroll
      for (int s = 0; s < 2; ++s) {
        FragU af;
        af.q = *(const i32x4*)(ldsA + (s * 8 + wm * 4 + mi) * 1024 + lane * 16);
#pragma unroll
        for (int ni = 0; ni < 4; ++ni)
          acc[mi][ni] = __builtin_amdgcn_mfma_f32_16x16x32_bf16(af.v, xf[s][ni].v, acc[mi][ni], 0, 0, 0);
      }
  }

  // accumulate into out (C/D layout: col=lane&15, row=(lane>>4)*4+r)
#pragma unroll
  for (int mi = 0; mi < 4; ++mi) {
    int grow = I * 128 + wm * 64 + mi * 16 + (lane >> 4) * 4;
#pragma unroll
    for (int ni = 0; ni < 4; ++ni) {
      int gcol = J * 128 + wn * 64 + ni * 16 + (lane & 15);
#pragma unroll
      for (int r = 0; r < 4; ++r)
        unsafeAtomicAdd(out + (size_t)(grow + r) * NCOLSX + gcol, acc[mi][ni][r]);
    }
  }
}

// ---------------- fallback (ws too small): plain fp32 -----------------------
__global__ __launch_bounds__(256) void naive_conv(
    const float* __restrict__ a, const float* __restrict__ x, float* __restrict__ out) {
  const int j = blockIdx.x * 256 + threadIdx.x;
  const int i0 = blockIdx.y * 32;
  float accv[32];
#pragma unroll
  for (int r = 0; r < 32; ++r) accv[r] = 0.f;
  for (int k = 0; k < i0; ++k) {
    float xv = x[(size_t)k * NCOLSX + j];
#pragma unroll
    for (int r = 0; r < 32; ++r) accv[r] += a[i0 + r - k] * xv;
  }
  for (int k = i0; k < i0 + 32; ++k) {
    float xv = x[(size_t)k * NCOLSX + j];
    for (int r = k - i0; r < 32; ++r) accv[r] += a[i0 + r - k] * xv;
  }
#pragma unroll
  for (int r = 0; r < 32; ++r) out[(size_t)(i0 + r) * NCOLSX + j] = accv[r];
}

extern "C" void kernel_launch(void* const* d_in, const int* in_sizes, int n_in,
                              void* d_out, int out_size, void* d_ws, size_t ws_size,
                              hipStream_t stream) {
  const float* a = (const float*)d_in[0];
  const float* x = (const float*)d_in[1];
  float* out = (float*)d_out;

  const size_t OFF_XH = 0;
  const size_t OFF_AH = (size_t)NROWS * NCOLSX * 2;       // 16 MiB
  const size_t NEEDED = OFF_AH + (size_t)128 * 16384;     // +2 MiB

  if (ws_size < NEEDED) {
    naive_conv<<<dim3(NCOLSX / 256, NROWS / 32), 256, 0, stream>>>(a, x, out);
    return;
  }

  char* ws = (char*)d_ws;
  unsigned short* xhT = (unsigned short*)(ws + OFF_XH);
  unsigned short* AhT = (unsigned short*)(ws + OFF_AH);

  hipMemsetAsync(d_out, 0, (size_t)NROWS * NCOLSX * sizeof(float), stream);
  bf16_transpose_x<<<dim3(NROWS / 64, NCOLSX / 64), 256, 0, stream>>>(x, xhT);
  build_atiles<<<128, 256, 0, stream>>>(a, AhT);
  conv_mfma<<<4352, 256, 0, stream>>>(xhT, AhT, out);
}

// Round 3
// 201.022 us; speedup vs baseline: 1.7875x; 1.5714x over previous
//
#include <hip/hip_runtime.h>
#include <math.h>

#define NROWS 8192
#define NCOLSX 1024

typedef __attribute__((ext_vector_type(8))) short bf16x8;
typedef __attribute__((ext_vector_type(4))) float f32x4;
typedef __attribute__((ext_vector_type(4))) int i32x4;
typedef __attribute__((ext_vector_type(4))) unsigned short u16x4;

union FragU { i32x4 q; bf16x8 v; };

__device__ __forceinline__ unsigned short bf16h(float f) {
  unsigned int u = __float_as_uint(f);
  unsigned int r = (u + 0x7FFFu + ((u >> 16) & 1u)) >> 16;
  return (unsigned short)r;
}

#define GLOAD16(gp, lp) __builtin_amdgcn_global_load_lds( \
    (const __attribute__((address_space(1))) void*)(gp),  \
    (__attribute__((address_space(3))) void*)(lp), 16, 0, 0)

// ---------------- fused prep: x->bf16-transpose  +  Toeplitz A-tiles --------
// blocks [0,2048): transpose 64x64 tile of x.  blocks [2048,2176): A-tile tau.
__global__ __launch_bounds__(256) void prep_fused(
    const float* __restrict__ x, const float* __restrict__ a,
    unsigned short* __restrict__ xhT, unsigned short* __restrict__ Ah) {
  __shared__ float tile[64][65];
  const int t = threadIdx.x;
  if (blockIdx.x < 2048) {
    const int bx = blockIdx.x;
    const int r0 = (bx & 127) * 64;   // n-dim
    const int c0 = (bx >> 7) * 64;    // d-dim
    const int tr = t >> 4, tc = t & 15;
#pragma unroll
    for (int rr = 0; rr < 4; ++rr) {
      int row = tr * 4 + rr;
      f32x4 v = *(const f32x4*)(x + (size_t)(r0 + row) * NCOLSX + c0 + tc * 4);
      tile[row][tc * 4 + 0] = v.x;
      tile[row][tc * 4 + 1] = v.y;
      tile[row][tc * 4 + 2] = v.z;
      tile[row][tc * 4 + 3] = v.w;
    }
    __syncthreads();
#pragma unroll
    for (int rr = 0; rr < 4; ++rr) {
      int j = tr * 4 + rr;
      u16x4 h;
#pragma unroll
      for (int c = 0; c < 4; ++c) h[c] = bf16h(tile[tc * 4 + c][j]);
      *(u16x4*)(xhT + (size_t)(c0 + j) * NROWS + r0 + tc * 4) = h;
    }
  } else {
    // A-tile tau (Delta = tau*64 - 64): frag-packed 128x64 values ext[Delta+row-k]
    // elem idx = (s*8+f)*512 + l*8 + e, value = ext[Delta+16f+(l&15)-s*32-(l>>4)*8-e]
    const int tau = blockIdx.x - 2048;   // 0..127
    const int delta = tau * 64 - 64;
#pragma unroll
    for (int n = 0; n < 32; ++n) {
      int idx = n * 256 + t;
      int e = idx & 7, l = (idx >> 3) & 63, sf = idx >> 9;
      int f = sf & 7, s = sf >> 3;
      int tt = delta + 16 * f + (l & 15) - s * 32 - (l >> 4) * 8 - e;
      float v = (tt >= 0 && tt < NROWS) ? a[tt] : 0.f;
      Ah[(size_t)tau * 8192 + idx] = bf16h(v);
    }
  }
}

// ---------------- main MFMA kernel: equal-work flattened chunks -------------
// Per J-column: triangle = 4160 K-steps (row I has 2(I+1) steps of k=64).
// Chunk = 33 contiguous steps; block walks rows, flushes acc at row/range end.
__global__ __launch_bounds__(256, 2) void conv_mfma(
    const unsigned short* __restrict__ xhT, const unsigned short* __restrict__ Ah,
    float* __restrict__ out) {
  __shared__ char lds[32768];
  char* ldsA = lds;          // 16KB frag-packed A tile
  char* ldsX = lds + 16384;  // 16KB: [s][row-half][64 rows][64B of k]

  const int t = threadIdx.x;
  const int lane = t & 63;
  const int wid = t >> 6;
  const int wm = wid >> 1, wn = wid & 1;

  const int J = blockIdx.x & 7;
  const int chunk = blockIdx.x >> 3;   // 0..126
  int g = chunk * 33;
  const int gend = (g + 33 < 4160) ? g + 33 : 4160;

  // decode start row: I(I+1) <= g < (I+1)(I+2)
  int I = (int)((sqrtf(4.f * (float)g + 1.f) - 1.f) * 0.5f);
  while ((I + 1) * (I + 2) <= g) ++I;
  while (I * (I + 1) > g) --I;

  f32x4 acc[4][4] = {};

  const char* Ah_b = (const char*)Ah;
  const char* xh_b = (const char*)xhT;

  size_t xsrc[4];
#pragma unroll
  for (int w = 0; w < 4; ++w)
    xsrc[w] = (size_t)(J * 128 + (w & 1) * 64 + (t >> 2)) * (NROWS * 2)
              + (w >> 1) * 64 + (t & 3) * 16;

  for (;;) {
    const int ks = g - I * (I + 1);
    const int k0 = ks * 64;
    const int tau = ((I * 128 - k0) >> 6) + 1;
    __syncthreads();
    const char* sA = Ah_b + (size_t)tau * 16384;
    const size_t koff = (size_t)k0 * 2;
#pragma unroll
    for (int w = 0; w < 4; ++w) {
      GLOAD16(sA + w * 4096 + t * 16, ldsA + w * 4096 + t * 16);
      GLOAD16(xh_b + xsrc[w] + koff, ldsX + w * 4096 + t * 16);
    }
    asm volatile("s_waitcnt vmcnt(0)" ::: "memory");
    __syncthreads();

    FragU xf[2][4];
#pragma unroll
    for (int s = 0; s < 2; ++s)
#pragma unroll
      for (int ni = 0; ni < 4; ++ni) {
        int off = s * 8192 + (wn * 64 + ni * 16 + (lane & 15)) * 64 + (lane >> 4) * 16;
        xf[s][ni].q = *(const i32x4*)(ldsX + off);
      }
#pragma unroll
    for (int mi = 0; mi < 4; ++mi)
#pragma unroll
      for (int s = 0; s < 2; ++s) {
        FragU af;
        af.q = *(const i32x4*)(ldsA + (s * 8 + wm * 4 + mi) * 1024 + lane * 16);
#pragma unroll
        for (int ni = 0; ni < 4; ++ni)
          acc[mi][ni] = __builtin_amdgcn_mfma_f32_16x16x32_bf16(af.v, xf[s][ni].v, acc[mi][ni], 0, 0, 0);
      }

    ++g;
    const bool rowEnd = (g == (I + 1) * (I + 2));
    if (rowEnd || g >= gend) {
      // flush acc -> out tile (I, J). C/D layout: col=lane&15, row=(lane>>4)*4+r
#pragma unroll
      for (int mi = 0; mi < 4; ++mi) {
        int grow = I * 128 + wm * 64 + mi * 16 + (lane >> 4) * 4;
#pragma unroll
        for (int ni = 0; ni < 4; ++ni) {
          int gcol = J * 128 + wn * 64 + ni * 16 + (lane & 15);
#pragma unroll
          for (int r = 0; r < 4; ++r)
            unsafeAtomicAdd(out + (size_t)(grow + r) * NCOLSX + gcol, acc[mi][ni][r]);
        }
      }
      if (g >= gend) break;
      ++I;
#pragma unroll
      for (int mi = 0; mi < 4; ++mi)
#pragma unroll
        for (int ni = 0; ni < 4; ++ni)
          acc[mi][ni] = f32x4{0.f, 0.f, 0.f, 0.f};
    }
  }
}

// ---------------- fallback (ws too small): plain fp32 -----------------------
__global__ __launch_bounds__(256) void naive_conv(
    const float* __restrict__ a, const float* __restrict__ x, float* __restrict__ out) {
  const int j = blockIdx.x * 256 + threadIdx.x;
  const int i0 = blockIdx.y * 32;
  float accv[32];
#pragma unroll
  for (int r = 0; r < 32; ++r) accv[r] = 0.f;
  for (int k = 0; k < i0; ++k) {
    float xv = x[(size_t)k * NCOLSX + j];
#pragma unroll
    for (int r = 0; r < 32; ++r) accv[r] += a[i0 + r - k] * xv;
  }
  for (int k = i0; k < i0 + 32; ++k) {
    float xv = x[(size_t)k * NCOLSX + j];
    for (int r = k - i0; r < 32; ++r) accv[r] += a[i0 + r - k] * xv;
  }
#pragma unroll
  for (int r = 0; r < 32; ++r) out[(size_t)(i0 + r) * NCOLSX + j] = accv[r];
}

extern "C" void kernel_launch(void* const* d_in, const int* in_sizes, int n_in,
                              void* d_out, int out_size, void* d_ws, size_t ws_size,
                              hipStream_t stream) {
  const float* a = (const float*)d_in[0];
  const float* x = (const float*)d_in[1];
  float* out = (float*)d_out;

  const size_t OFF_XH = 0;
  const size_t OFF_AH = (size_t)NROWS * NCOLSX * 2;       // 16 MiB
  const size_t NEEDED = OFF_AH + (size_t)128 * 16384;     // +2 MiB

  if (ws_size < NEEDED) {
    naive_conv<<<dim3(NCOLSX / 256, NROWS / 32), 256, 0, stream>>>(a, x, out);
    return;
  }

  char* ws = (char*)d_ws;
  unsigned short* xhT = (unsigned short*)(ws + OFF_XH);
  unsigned short* AhT = (unsigned short*)(ws + OFF_AH);

  hipMemsetAsync(d_out, 0, (size_t)NROWS * NCOLSX * sizeof(float), stream);
  prep_fused<<<2176, 256, 0, stream>>>(x, a, xhT, AhT);
  conv_mfma<<<1016, 256, 0, stream>>>(xhT, AhT, out);
}